// Round 8
// baseline (238.309 us; speedup 1.0000x reference)
//
#include <hip/hip_runtime.h>
#include <stdint.h>

// SimpleSelfAttention B=4, N=2048, E=512 (fp32 in/out) via bf16(-split) MFMA.
// split: a*b ~= ah*bh + ah*bl + al*bh (3-seg NT GEMM).
// R8 pipeline (k-projection eliminated algebraically):
//   H = Wk^T@Wq (3-seg, bf16)         [energy = query@(Wq^T Wk)@key^T]
//   Wov = Wo@Wv (3-seg, split out)    [V-proj eliminated: out = U@(Wov@val^T)^T/S]
//   t = query@H^T (1-seg bf16) -> U = exp2(t.key^T*c) (1-seg; rowsums S atomics)
//   WV = Wov@value^T (3-seg — accuracy backbone, stays)  -> out = U@WV^T/S + bo
// Error model (empirical absmax pinned at WVh bf16 ulp): WV path 3-seg,
// logit path plain bf16 (softmax cancels/averages it; R8 path has FEWER
// rounding units than R7: t=3,key=1 vs q=3,k=3).

typedef __bf16 bf16;
typedef __bf16 bf16x8 __attribute__((ext_vector_type(8)));
typedef float f32x4 __attribute__((ext_vector_type(4)));

#define GLB_AS __attribute__((address_space(1)))
#define LDS_AS __attribute__((address_space(3)))

struct GArgs {
    const bf16* a[3];
    const bf16* b[3];
    long zsa, zsb, zso;   // grid.z strides (elements)
    int lda, ldb, ldo;    // row strides (elements)
    void* out0;           // EPI 0/2: f32 | EPI 1: bf16 hi | EPI 3/4: bf16
    void* out1;           // EPI 1: bf16 lo
    const float* bias;    // EPI 0/2
    const float* srow;    // EPI 2: out *= 1/srow[z*2048+row]
    float* Sout;          // EPI 4: atomic row sums of exp
    float escale;         // EPI 4: U = exp2(x*escale)
};

// NT GEMM: C[m,n] = sum_seg sum_k A_seg[m,k] * B_seg[n,k]
// 256 threads = 4 waves (2x2), 16x16x32 bf16 MFMA, BK=64, XOR-swizzled staging.
// EPI: 0=f32(+bias) 1=bf16 hi/lo split 2=f32*(1/S)+bias 3=bf16 4=bf16 exp2+rowsum
// SWZ (XCD locality remap, assumes %8 round-robin dispatch):
//   0=none  1=grid(16,16)  2=grid(4,64)  3=grid(8,16)  4=grid(4,16)
template<int BM, int BN, int NSEG, int KSEG, int EPI, int SWZ>
__global__ __launch_bounds__(256) void gemm_mfma(GArgs g)
{
    constexpr int KT = KSEG / 64;
    constexpr int WM = BM / 2, WN = BN / 2;
    constexpr int FM = WM / 16, FN = WN / 16;
    constexpr int APASS = BM / 32, BPASS = BN / 32;
    constexpr bool REPACK = (EPI == 1 || EPI == 3 || EPI == 4);
    constexpr int RSTR = WN + 8;
    constexpr int SSTAGE = (BM + BN) * 64 * 2;
    constexpr int SREP = REPACK ? 4 * WM * RSTR * 2 : 0;
    constexpr int SBYTES = SSTAGE > SREP ? SSTAGE : SREP;
    __shared__ char smem[SBYTES];
    bf16* As = (bf16*)smem;
    bf16* Bs = As + BM * 64;

    const int tid = threadIdx.x, lane = tid & 63, wave = tid >> 6;
    const int z = blockIdx.z;
    int bx = blockIdx.x, by = blockIdx.y;
    if constexpr (SWZ == 1) {            // grid (16,16)
        const int lin = bx + (by << 4);
        const int gx = lin & 7, s = lin >> 3;        // s in [0,32)
        bx = (gx & 3) * 4 + (s & 3);
        by = (gx >> 2) * 8 + (s >> 2);
    } else if constexpr (SWZ == 2) {     // grid (4,64)
        const int lin = bx + (by << 2);
        const int gx = lin & 7, s = lin >> 3;        // s in [0,32)
        bx = s & 3;
        by = gx * 8 + (s >> 2);
    } else if constexpr (SWZ == 3) {     // grid (8,16)
        const int lin = bx + (by << 3);
        const int gx = lin & 7, s = lin >> 3;        // s in [0,16)
        bx = s & 7;
        by = gx * 2 + (s >> 3);
    } else if constexpr (SWZ == 4) {     // grid (4,16)
        const int lin = bx + (by << 2);
        const int gx = lin & 7, s = lin >> 3;        // s in [0,8)
        bx = s & 3;
        by = gx * 2 + (s >> 2);
    }
    const int m0 = by * BM, n0 = bx * BN;
    const int wm = (wave & 1) * WM, wn = (wave >> 1) * WN;
    const int srow = tid >> 3;                       // staging row (32-row pass)
    const int scol = ((tid & 7) ^ (srow & 7)) * 8;   // xor-swizzled k-chunk

    f32x4 acc[FM][FN] = {};

#pragma unroll
    for (int seg = 0; seg < NSEG; ++seg) {
        const bf16* ap = g.a[seg] + (long)z * g.zsa + (long)(m0 + srow) * g.lda + scol;
        const bf16* bp = g.b[seg] + (long)z * g.zsb + (long)(n0 + srow) * g.ldb + scol;
        for (int kt = 0; kt < KT; ++kt) {
            const int k0 = kt * 64;
            __syncthreads();
#pragma unroll
            for (int p = 0; p < APASS; ++p)
                __builtin_amdgcn_global_load_lds(
                    (const GLB_AS uint32_t*)(ap + k0 + (long)p * 32 * g.lda),
                    (LDS_AS uint32_t*)(As + p * 2048 + tid * 8), 16, 0, 0);
#pragma unroll
            for (int p = 0; p < BPASS; ++p)
                __builtin_amdgcn_global_load_lds(
                    (const GLB_AS uint32_t*)(bp + k0 + (long)p * 32 * g.ldb),
                    (LDS_AS uint32_t*)(Bs + p * 2048 + tid * 8), 16, 0, 0);
            __syncthreads();
#pragma unroll
            for (int kk = 0; kk < 2; ++kk) {
                bf16x8 af[FM], bfr[FN];
#pragma unroll
                for (int i = 0; i < FM; ++i) {
                    const int row = wm + i * 16 + (lane & 15);
                    af[i] = *(const bf16x8*)&As[row * 64 + ((kk * 4 + (lane >> 4)) ^ (lane & 7)) * 8];
                }
#pragma unroll
                for (int j = 0; j < FN; ++j) {
                    const int row = wn + j * 16 + (lane & 15);
                    bfr[j] = *(const bf16x8*)&Bs[row * 64 + ((kk * 4 + (lane >> 4)) ^ (lane & 7)) * 8];
                }
#pragma unroll
                for (int i = 0; i < FM; ++i)
#pragma unroll
                    for (int j = 0; j < FN; ++j)
                        acc[i][j] = __builtin_amdgcn_mfma_f32_16x16x32_bf16(af[i], bfr[j], acc[i][j], 0, 0, 0);
            }
        }
    }

    // C/D layout (m89/m91): col = lane&15, row = (lane>>4)*4 + reg
    const int col = lane & 15, qd = lane >> 4;

    if constexpr (EPI == 0 || EPI == 2) {
#pragma unroll
        for (int i = 0; i < FM; ++i)
#pragma unroll
            for (int r = 0; r < 4; ++r) {
                const long gm = m0 + wm + i * 16 + qd * 4 + r;
                float rowscale = 1.0f;
                if (EPI == 2) rowscale = 1.0f / g.srow[(long)z * 2048 + gm];
#pragma unroll
                for (int j = 0; j < FN; ++j) {
                    const long gn = n0 + wn + j * 16 + col;
                    const float x = acc[i][j][r];
                    float* o = (float*)g.out0 + (long)z * g.zso;
                    if (EPI == 0) o[gm * g.ldo + gn] = g.bias ? (x + g.bias[gn]) : x;
                    else          o[gm * g.ldo + gn] = fmaf(x, rowscale, g.bias[gn]);
                }
            }
    } else {
        if constexpr (EPI == 4) {
#pragma unroll
            for (int i = 0; i < FM; ++i)
#pragma unroll
                for (int j = 0; j < FN; ++j)
#pragma unroll
                    for (int r = 0; r < 4; ++r)
                        acc[i][j][r] = exp2f(acc[i][j][r] * g.escale);
#pragma unroll
            for (int i = 0; i < FM; ++i)
#pragma unroll
                for (int r = 0; r < 4; ++r) {
                    float s = 0.f;
#pragma unroll
                    for (int j = 0; j < FN; ++j) s += acc[i][j][r];
#pragma unroll
                    for (int off = 1; off < 16; off <<= 1) s += __shfl_xor(s, off, 64);
                    if ((lane & 15) == 0)
                        atomicAdd(g.Sout + (long)z * 2048 + m0 + wm + i * 16 + qd * 4 + r, s);
                }
        }
        __syncthreads();                 // staging LDS dead for all waves
        bf16* wa = (bf16*)smem + wave * WM * RSTR;
        constexpr int NP = (EPI == 1) ? 2 : 1;
        constexpr int CPR = WN / 8;      // 8-elem chunks per row
        constexpr int RPI = 64 / CPR;    // rows per store iteration
        static_assert(WM % RPI == 0, "repack rows");
#pragma unroll
        for (int pass = 0; pass < NP; ++pass) {
#pragma unroll
            for (int i = 0; i < FM; ++i)
#pragma unroll
                for (int j = 0; j < FN; ++j)
#pragma unroll
                    for (int r = 0; r < 4; ++r) {
                        const float x = acc[i][j][r];
                        bf16 v;
                        if (EPI == 1) {
                            const bf16 h = (bf16)x;
                            v = pass ? (bf16)(x - (float)h) : h;
                        } else {
                            v = (bf16)x;
                        }
                        wa[(i * 16 + qd * 4 + r) * RSTR + j * 16 + col] = v;
                    }
            bf16* outp = ((pass == 0) ? (bf16*)g.out0 : (bf16*)g.out1) + (long)z * g.zso;
#pragma unroll
            for (int t = 0; t < WM / RPI; ++t) {
                const int rr = t * RPI + (lane / CPR);
                const int cc = (lane % CPR) * 8;
                bf16x8 vv = *(const bf16x8*)&wa[rr * RSTR + cc];
                *(bf16x8*)(outp + (long)(m0 + wm + rr) * g.ldo + n0 + wn + cc) = vv;
            }
            if (NP == 2) asm volatile("s_waitcnt lgkmcnt(0)" ::: "memory");
        }
    }
}

// fp32 -> bf16 hi (always) + lo (if bit z of lomask); per-z length n[z];
// z==0 also zeros S (8192 f32)
struct SplitArgs {
    const float* x[4];
    bf16* h[4];
    bf16* l[4];
    float* S;
    long n[4];
    int lomask;
};
__global__ __launch_bounds__(256) void split_f32(SplitArgs s)
{
    const int z = blockIdx.z;
    if (s.S && z == 0 && blockIdx.x < 16) {
        const long si = (long)blockIdx.x * 256 + threadIdx.x;   // 16*256 float2 = 8192 f32
        ((float2*)s.S)[si] = make_float2(0.f, 0.f);
    }
    const long i = ((long)blockIdx.x * 256 + threadIdx.x) * 8;
    if (i >= s.n[z]) return;
    const float* x = s.x[z];
    float4 a = *(const float4*)(x + i);
    float4 b = *(const float4*)(x + i + 4);
    float vv[8] = {a.x, a.y, a.z, a.w, b.x, b.y, b.z, b.w};
    union { bf16 v[8]; bf16x8 v8; } uh, ul;
#pragma unroll
    for (int j = 0; j < 8; ++j) {
        bf16 hh = (bf16)vv[j];
        uh.v[j] = hh;
        ul.v[j] = (bf16)(vv[j] - (float)hh);
    }
    *(bf16x8*)(s.h[z] + i) = uh.v8;
    if (s.lomask & (1 << z)) *(bf16x8*)(s.l[z] + i) = ul.v8;
}

// W [512,512] fp32 -> transposed bf16 split: Th/Tl[d,e] = split(W[e,d]); z-batched
struct TransArgs {
    const float* x[3];
    bf16* th[3];
    bf16* tl[3];
};
__global__ __launch_bounds__(256) void transpose_split_w(TransArgs t3)
{
    __shared__ float t[64][65];
    const int z = blockIdx.z;
    const float* W = t3.x[z];
    bf16* Th = t3.th[z];
    bf16* Tl = t3.tl[z];
    const int e0 = blockIdx.y * 64, d0 = blockIdx.x * 64;
#pragma unroll 4
    for (int i = 0; i < 16; ++i) {
        int idx = i * 256 + threadIdx.x;
        int r = idx >> 6, c = idx & 63;
        t[r][c] = W[(long)(e0 + r) * 512 + d0 + c];
    }
    __syncthreads();
#pragma unroll
    for (int i = 0; i < 2; ++i) {
        int idx = i * 256 + threadIdx.x;          // 0..511
        int r = idx >> 3, c = (idx & 7) * 8;      // r = d offset, c = e offset
        union { bf16 v[8]; bf16x8 v8; } uh, ul;
#pragma unroll
        for (int j = 0; j < 8; ++j) {
            float x = t[c + j][r];
            bf16 hh = (bf16)x;
            uh.v[j] = hh;
            ul.v[j] = (bf16)(x - (float)hh);
        }
        *(bf16x8*)(Th + (long)(d0 + r) * 512 + e0 + c) = uh.v8;
        *(bf16x8*)(Tl + (long)(d0 + r) * 512 + e0 + c) = ul.v8;
    }
}

// ---------------- fp32 fallback (round-1, known-correct) ----------------
#define TILE 64
#define BKF 16
#define PADF 4

__global__ __launch_bounds__(256) void gemm_nt(
    const float* __restrict__ A, const float* __restrict__ B,
    float* __restrict__ C, const float* __restrict__ bias,
    int M, int N, int K, float alpha)
{
    __shared__ float As[BKF][TILE + PADF];
    __shared__ float Bs[BKF][TILE + PADF];
    const int tid = threadIdx.x;
    const int m0 = blockIdx.y * TILE;
    const int n0 = blockIdx.x * TILE;
    const int lr = tid >> 2;
    const int lk = (tid & 3) << 2;
    const int tm = (tid >> 4) << 2;
    const int tn = (tid & 15) << 2;

    float acc[4][4] = {};
    const float* ap = A + (long)(m0 + lr) * K + lk;
    const float* bp = B + (long)(n0 + lr) * K + lk;

    for (int k0 = 0; k0 < K; k0 += BKF) {
        float4 av = *(const float4*)(ap + k0);
        float4 bv = *(const float4*)(bp + k0);
        As[lk + 0][lr] = av.x; As[lk + 1][lr] = av.y;
        As[lk + 2][lr] = av.z; As[lk + 3][lr] = av.w;
        Bs[lk + 0][lr] = bv.x; Bs[lk + 1][lr] = bv.y;
        Bs[lk + 2][lr] = bv.z; Bs[lk + 3][lr] = bv.w;
        __syncthreads();
#pragma unroll
        for (int kk = 0; kk < BKF; ++kk) {
            float4 a4 = *(const float4*)&As[kk][tm];
            float4 b4 = *(const float4*)&Bs[kk][tn];
            float aa[4] = {a4.x, a4.y, a4.z, a4.w};
            float bb[4] = {b4.x, b4.y, b4.z, b4.w};
#pragma unroll
            for (int i = 0; i < 4; ++i)
#pragma unroll
                for (int j = 0; j < 4; ++j)
                    acc[i][j] = fmaf(aa[i], bb[j], acc[i][j]);
        }
        __syncthreads();
    }

    float4 b4 = make_float4(0.f, 0.f, 0.f, 0.f);
    if (bias) b4 = *(const float4*)(bias + n0 + tn);
#pragma unroll
    for (int i = 0; i < 4; ++i) {
        float4 o;
        o.x = fmaf(acc[i][0], alpha, b4.x);
        o.y = fmaf(acc[i][1], alpha, b4.y);
        o.z = fmaf(acc[i][2], alpha, b4.z);
        o.w = fmaf(acc[i][3], alpha, b4.w);
        *(float4*)(C + (long)(m0 + tm + i) * N + n0 + tn) = o;
    }
}

__global__ __launch_bounds__(256) void gemm_nn(
    const float* __restrict__ A, const float* __restrict__ B,
    float* __restrict__ C, int M, int N, int K)
{
    __shared__ float As[BKF][TILE + PADF];
    __shared__ float Bs[BKF][TILE + PADF];
    const int tid = threadIdx.x;
    const int m0 = blockIdx.y * TILE;
    const int n0 = blockIdx.x * TILE;
    const int lr = tid >> 2;
    const int lk = (tid & 3) << 2;
    const int bkk = tid >> 4;
    const int bn = (tid & 15) << 2;
    const int tm = (tid >> 4) << 2;
    const int tn = (tid & 15) << 2;

    float acc[4][4] = {};
    const float* ap = A + (long)(m0 + lr) * K + lk;
    const float* bp = B + (long)bkk * N + n0 + bn;

    for (int k0 = 0; k0 < K; k0 += BKF) {
        float4 av = *(const float4*)(ap + k0);
        As[lk + 0][lr] = av.x; As[lk + 1][lr] = av.y;
        As[lk + 2][lr] = av.z; As[lk + 3][lr] = av.w;
        float4 bv = *(const float4*)(bp + (long)k0 * N);
        *(float4*)&Bs[bkk][bn] = bv;
        __syncthreads();
#pragma unroll
        for (int kk = 0; kk < BKF; ++kk) {
            float4 a4 = *(const float4*)&As[kk][tm];
            float4 b4 = *(const float4*)&Bs[kk][tn];
            float aa[4] = {a4.x, a4.y, a4.z, a4.w};
            float bb[4] = {b4.x, b4.y, b4.z, b4.w};
#pragma unroll
            for (int i = 0; i < 4; ++i)
#pragma unroll
                for (int j = 0; j < 4; ++j)
                    acc[i][j] = fmaf(aa[i], bb[j], acc[i][j]);
        }
        __syncthreads();
    }

#pragma unroll
    for (int i = 0; i < 4; ++i) {
        float4 o = make_float4(acc[i][0], acc[i][1], acc[i][2], acc[i][3]);
        *(float4*)(C + (long)(m0 + tm + i) * N + n0 + tn) = o;
    }
}

__global__ __launch_bounds__(256) void softmax2048(float* __restrict__ E)
{
    const float c = 0.04419417382415922f * 1.44269504088896341f;
    float* p = E + (long)blockIdx.x * 2048;
    const int tid = threadIdx.x;
    float4 r0 = *(const float4*)(p + tid * 8);
    float4 r1 = *(const float4*)(p + tid * 8 + 4);
    float x[8] = {r0.x, r0.y, r0.z, r0.w, r1.x, r1.y, r1.z, r1.w};

    float m = x[0];
#pragma unroll
    for (int i = 1; i < 8; ++i) m = fmaxf(m, x[i]);
#pragma unroll
    for (int off = 32; off > 0; off >>= 1) m = fmaxf(m, __shfl_down(m, off, 64));

    __shared__ float red[4];
    const int lane = tid & 63, wid = tid >> 6;
    if (lane == 0) red[wid] = m;
    __syncthreads();
    m = fmaxf(fmaxf(red[0], red[1]), fmaxf(red[2], red[3]));

    float s = 0.f;
#pragma unroll
    for (int i = 0; i < 8; ++i) {
        x[i] = exp2f((x[i] - m) * c);
        s += x[i];
    }
#pragma unroll
    for (int off = 32; off > 0; off >>= 1) s += __shfl_down(s, off, 64);
    __syncthreads();
    if (lane == 0) red[wid] = s;
    __syncthreads();
    s = red[0] + red[1] + red[2] + red[3];
    const float inv = 1.0f / s;

    r0 = make_float4(x[0] * inv, x[1] * inv, x[2] * inv, x[3] * inv);
    r1 = make_float4(x[4] * inv, x[5] * inv, x[6] * inv, x[7] * inv);
    *(float4*)(p + tid * 8) = r0;
    *(float4*)(p + tid * 8 + 4) = r1;
}

// ------------------------------------------------------------------------

extern "C" void kernel_launch(void* const* d_in, const int* in_sizes, int n_in,
                              void* d_out, int out_size, void* d_ws, size_t ws_size,
                              hipStream_t stream)
{
    const int Bb = 4, Nn = 2048, E = 512;
    const int M = Bb * Nn;                       // 8192
    const float* value = (const float*)d_in[0];
    const float* key_  = (const float*)d_in[1];
    const float* query = (const float*)d_in[2];
    const float* Wq = (const float*)d_in[3];
    const float* Wk = (const float*)d_in[4];
    const float* Wv = (const float*)d_in[5];
    const float* Wo = (const float*)d_in[6];
    const float* bo = (const float*)d_in[7];
    float* out = (float*)d_out;

    const long ME = (long)M * E;                 // 4,194,304
    const long NE = (long)Nn * E;                // 1,048,576
    const long NN = (long)Nn * Nn;               // 4,194,304
    const long EE = (long)E * E;                 // 262,144
    const size_t EE2 = 524288;                   // EE bf16 bytes

    // weight block: [Woh|WkTh][Wol|WkTl][WvTh|WqTh][WvTl|WqTl][Wovh|Hh][Wovl|Hl]
    const size_t oWB  = 0;                        // 12 * EE2 = 6,291,456
    const size_t oQh  = oWB + 12 * EE2;           // ME*2 = 8,388,608
    const size_t oKh  = oQh + 8388608;
    const size_t oVh  = oKh + 8388608;
    const size_t oVl  = oVh + 8388608;
    const size_t oT   = oVl + 8388608;            // t: ME*2
    const size_t oU   = oT  + 8388608;            // 4*NN*2 = 33,554,432
    const size_t oS   = oU  + 33554432;           // 32,768
    const size_t oWV  = oS  + 32768;              // 4*NE*2 = 8,388,608
    const size_t REQ  = oWV + 8388608;            // 90,210,304

    if (ws_size < REQ) {
        // ---- fp32 fallback path (round-1, known-correct) ----
        float* q  = (float*)d_ws;
        float* k  = q  + ME;
        float* v  = k  + ME;
        float* en = v  + ME;
        float* ao = en + NN;
        const dim3 blk(256, 1, 1);
        gemm_nt<<<dim3(E / TILE, M / TILE, 1), blk, 0, stream>>>(query, Wq, q, nullptr, M, E, E, 1.0f);
        gemm_nt<<<dim3(E / TILE, M / TILE, 1), blk, 0, stream>>>(key_,  Wk, k, nullptr, M, E, E, 1.0f);
        gemm_nt<<<dim3(E / TILE, M / TILE, 1), blk, 0, stream>>>(value, Wv, v, nullptr, M, E, E, 1.0f);
        for (int b = 0; b < Bb; ++b) {
            const float* qb = q + (long)b * NE;
            const float* kb = k + (long)b * NE;
            const float* vb = v + (long)b * NE;
            float* aob = ao + (long)b * NE;
            gemm_nt<<<dim3(Nn / TILE, Nn / TILE, 1), blk, 0, stream>>>(qb, kb, en, nullptr, Nn, Nn, E, 1.0f);
            softmax2048<<<dim3(Nn, 1, 1), blk, 0, stream>>>(en);
            gemm_nn<<<dim3(E / TILE, Nn / TILE, 1), blk, 0, stream>>>(en, vb, aob, Nn, E, Nn);
        }
        gemm_nt<<<dim3(E / TILE, M / TILE, 1), blk, 0, stream>>>(ao, Wo, out, bo, M, E, E, 1.0f);
        return;
    }

    char* wb = (char*)d_ws + oWB;
    bf16* Woh  = (bf16*)(wb + 0 * EE2);
    bf16* WkTh = (bf16*)(wb + 1 * EE2);
    bf16* Wol  = (bf16*)(wb + 2 * EE2);
    bf16* WkTl = (bf16*)(wb + 3 * EE2);
    bf16* WvTh = (bf16*)(wb + 4 * EE2);
    bf16* WqTh = (bf16*)(wb + 5 * EE2);
    bf16* WvTl = (bf16*)(wb + 6 * EE2);
    bf16* WqTl = (bf16*)(wb + 7 * EE2);
    bf16* Wovh = (bf16*)(wb + 8 * EE2);
    bf16* Hh   = (bf16*)(wb + 9 * EE2);
    bf16* Wovl = (bf16*)(wb + 10 * EE2);   // (Hl at 11*EE2, computed but unused)
    bf16* qh   = (bf16*)((char*)d_ws + oQh);     // query bf16
    bf16* kh   = (bf16*)((char*)d_ws + oKh);     // key bf16
    bf16* vh   = (bf16*)((char*)d_ws + oVh);     // value hi
    bf16* vl   = (bf16*)((char*)d_ws + oVl);     // value lo
    bf16* tq   = (bf16*)((char*)d_ws + oT);      // t = query@H^T
    bf16* U    = (bf16*)((char*)d_ws + oU);      // [4][2048][2048]
    float* S   = (float*)((char*)d_ws + oS);     // [8192]
    bf16* WVh  = (bf16*)((char*)d_ws + oWV);     // [4][512][2048]

    // 1) converts: query,key (hi), value (hi+lo), Wo (hi+lo); zero S
    {
        SplitArgs s{};
        s.x[0] = query; s.x[1] = key_; s.x[2] = value; s.x[3] = Wo;
        s.h[0] = qh; s.h[1] = kh; s.h[2] = vh; s.h[3] = Woh;
        s.l[2] = vl; s.l[3] = Wol;
        s.S = S;
        s.n[0] = ME; s.n[1] = ME; s.n[2] = ME; s.n[3] = EE;
        s.lomask = 0b1100;
        split_f32<<<dim3((unsigned)(ME / 2048), 1, 4), 256, 0, stream>>>(s);
    }
    // 2) transposed splits: Wv, Wq, Wk
    {
        TransArgs t3{};
        t3.x[0] = Wv; t3.x[1] = Wq; t3.x[2] = Wk;
        t3.th[0] = WvTh; t3.th[1] = WqTh; t3.th[2] = WkTh;
        t3.tl[0] = WvTl; t3.tl[1] = WqTl; t3.tl[2] = WkTl;
        transpose_split_w<<<dim3(8, 8, 3), 256, 0, stream>>>(t3);
    }
    // 3) z=0: Wov = Wo@Wv ; z=1: H = Wk^T@Wq  (3-seg NT, split epilogue)
    {
        GArgs g{};
        g.a[0] = Woh;  g.a[1] = Woh;  g.a[2] = Wol;
        g.b[0] = WvTh; g.b[1] = WvTl; g.b[2] = WvTh;
        g.zsa = EE; g.zsb = EE; g.zso = EE;
        g.lda = E; g.ldb = E; g.ldo = E;
        g.out0 = Wovh; g.out1 = Wovl;
        gemm_mfma<64, 64, 3, 512, 1, 0><<<dim3(8, 8, 2), 256, 0, stream>>>(g);
    }
    // 4) t = query @ H^T  (plain 1-seg bf16)
    {
        GArgs g{};
        g.a[0] = qh;
        g.b[0] = Hh;
        g.lda = E; g.ldb = E; g.ldo = E;
        g.out0 = tq;
        gemm_mfma<128, 128, 1, 512, 3, 2><<<dim3(4, 64, 1), 256, 0, stream>>>(g);
    }
    // 5) energy: U = bf16(exp2((t.key^T)*c)), rowsums S via atomics
    {
        GArgs g{};
        g.a[0] = tq;
        g.b[0] = kh;
        g.zsa = NE; g.zsb = NE; g.zso = NN;
        g.lda = E; g.ldb = E; g.ldo = Nn;
        g.out0 = U; g.Sout = S;
        g.escale = 0.06375973295152033f; // (1/sqrt(512)) * log2(e)
        gemm_mfma<128, 128, 1, 512, 4, 1><<<dim3(16, 16, 4), 256, 0, stream>>>(g);
    }
    // 6) WV[f,k] = sum_e Wov[f,e] * value[k,e]  (3-seg — accuracy backbone)
    {
        GArgs g{};
        g.a[0] = Wovh; g.a[1] = Wovh; g.a[2] = Wovl;
        g.b[0] = vh;   g.b[1] = vl;   g.b[2] = vh;
        g.zsa = 0; g.zsb = NE; g.zso = NE;
        g.lda = E; g.ldb = E; g.ldo = Nn;
        g.out0 = WVh;
        gemm_mfma<128, 128, 3, 512, 3, 0><<<dim3(Nn / 128, E / 128, Bb), 256, 0, stream>>>(g);
    }
    // 7) out[q,f] = (sum_k U[q,k] * WV[f,k]) / S[q] + bo[f]
    {
        GArgs g{};
        g.a[0] = U; g.b[0] = WVh;
        g.zsa = NN; g.zsb = NE; g.zso = NE;
        g.lda = Nn; g.ldb = Nn; g.ldo = E;
        g.out0 = out; g.bias = bo; g.srow = S;
        gemm_mfma<128, 128, 1, 2048, 2, 4><<<dim3(E / 128, Nn / 128, Bb), 256, 0, stream>>>(g);
    }
}

// Round 9
// 216.495 us; speedup vs baseline: 1.1008x; 1.1008x over previous
//
#include <hip/hip_runtime.h>
#include <stdint.h>

// SimpleSelfAttention B=4, N=2048, E=512 (fp32 in/out) via bf16(-split) MFMA.
// split: a*b ~= ah*bh + ah*bl + al*bh (3-seg NT GEMM).
// R9 = R8 pipeline with R7 grids (>=2 blocks/CU for WV & PV — R8's 128x128
// tiles at 256 blocks = 1/CU dropped occupancy to 9% and cost 25 us):
//   H = Wk^T@Wq (3-seg, bf16)         [energy = query@(Wq^T Wk)@key^T]
//   Wov = Wo@Wv (3-seg, split out)    [V-proj eliminated]
//   t = query@H^T (1-seg bf16) -> U = exp2(t.key^T*c) (1-seg; rowsums S atomics)
//   WV = Wov@value^T (3-seg — accuracy backbone)  -> out = U@WV^T/S + bo

typedef __bf16 bf16;
typedef __bf16 bf16x8 __attribute__((ext_vector_type(8)));
typedef float f32x4 __attribute__((ext_vector_type(4)));

#define GLB_AS __attribute__((address_space(1)))
#define LDS_AS __attribute__((address_space(3)))

struct GArgs {
    const bf16* a[3];
    const bf16* b[3];
    long zsa, zsb, zso;   // grid.z strides (elements)
    int lda, ldb, ldo;    // row strides (elements)
    void* out0;           // EPI 0/2: f32 | EPI 1: bf16 hi | EPI 3/4: bf16
    void* out1;           // EPI 1: bf16 lo
    const float* bias;    // EPI 0/2
    const float* srow;    // EPI 2: out *= 1/srow[z*2048+row]
    float* Sout;          // EPI 4: atomic row sums of exp
    float escale;         // EPI 4: U = exp2(x*escale)
};

// NT GEMM: C[m,n] = sum_seg sum_k A_seg[m,k] * B_seg[n,k]
// 256 threads = 4 waves (2x2), 16x16x32 bf16 MFMA, BK=64, XOR-swizzled staging.
// EPI: 0=f32(+bias) 1=bf16 hi/lo split 2=f32*(1/S)+bias 3=bf16 4=bf16 exp2+rowsum
// SWZ (XCD locality remap, assumes %8 round-robin dispatch):
//   0=none  1=grid(16,16)  2=grid(4,64)  3=grid(8,16)
template<int BM, int BN, int NSEG, int KSEG, int EPI, int SWZ>
__global__ __launch_bounds__(256) void gemm_mfma(GArgs g)
{
    constexpr int KT = KSEG / 64;
    constexpr int WM = BM / 2, WN = BN / 2;
    constexpr int FM = WM / 16, FN = WN / 16;
    constexpr int APASS = BM / 32, BPASS = BN / 32;
    constexpr bool REPACK = (EPI == 1 || EPI == 3 || EPI == 4);
    constexpr int RSTR = WN + 8;
    constexpr int SSTAGE = (BM + BN) * 64 * 2;
    constexpr int SREP = REPACK ? 4 * WM * RSTR * 2 : 0;
    constexpr int SBYTES = SSTAGE > SREP ? SSTAGE : SREP;
    __shared__ char smem[SBYTES];
    bf16* As = (bf16*)smem;
    bf16* Bs = As + BM * 64;

    const int tid = threadIdx.x, lane = tid & 63, wave = tid >> 6;
    const int z = blockIdx.z;
    int bx = blockIdx.x, by = blockIdx.y;
    if constexpr (SWZ == 1) {            // grid (16,16)
        const int lin = bx + (by << 4);
        const int gx = lin & 7, s = lin >> 3;        // s in [0,32)
        bx = (gx & 3) * 4 + (s & 3);
        by = (gx >> 2) * 8 + (s >> 2);
    } else if constexpr (SWZ == 2) {     // grid (4,64)
        const int lin = bx + (by << 2);
        const int gx = lin & 7, s = lin >> 3;        // s in [0,32)
        bx = s & 3;
        by = gx * 8 + (s >> 2);
    } else if constexpr (SWZ == 3) {     // grid (8,16)
        const int lin = bx + (by << 3);
        const int gx = lin & 7, s = lin >> 3;        // s in [0,16)
        bx = s & 7;
        by = gx * 2 + (s >> 3);
    }
    const int m0 = by * BM, n0 = bx * BN;
    const int wm = (wave & 1) * WM, wn = (wave >> 1) * WN;
    const int srow = tid >> 3;                       // staging row (32-row pass)
    const int scol = ((tid & 7) ^ (srow & 7)) * 8;   // xor-swizzled k-chunk

    f32x4 acc[FM][FN] = {};

#pragma unroll
    for (int seg = 0; seg < NSEG; ++seg) {
        const bf16* ap = g.a[seg] + (long)z * g.zsa + (long)(m0 + srow) * g.lda + scol;
        const bf16* bp = g.b[seg] + (long)z * g.zsb + (long)(n0 + srow) * g.ldb + scol;
        for (int kt = 0; kt < KT; ++kt) {
            const int k0 = kt * 64;
            __syncthreads();
#pragma unroll
            for (int p = 0; p < APASS; ++p)
                __builtin_amdgcn_global_load_lds(
                    (const GLB_AS uint32_t*)(ap + k0 + (long)p * 32 * g.lda),
                    (LDS_AS uint32_t*)(As + p * 2048 + tid * 8), 16, 0, 0);
#pragma unroll
            for (int p = 0; p < BPASS; ++p)
                __builtin_amdgcn_global_load_lds(
                    (const GLB_AS uint32_t*)(bp + k0 + (long)p * 32 * g.ldb),
                    (LDS_AS uint32_t*)(Bs + p * 2048 + tid * 8), 16, 0, 0);
            __syncthreads();
#pragma unroll
            for (int kk = 0; kk < 2; ++kk) {
                bf16x8 af[FM], bfr[FN];
#pragma unroll
                for (int i = 0; i < FM; ++i) {
                    const int row = wm + i * 16 + (lane & 15);
                    af[i] = *(const bf16x8*)&As[row * 64 + ((kk * 4 + (lane >> 4)) ^ (lane & 7)) * 8];
                }
#pragma unroll
                for (int j = 0; j < FN; ++j) {
                    const int row = wn + j * 16 + (lane & 15);
                    bfr[j] = *(const bf16x8*)&Bs[row * 64 + ((kk * 4 + (lane >> 4)) ^ (lane & 7)) * 8];
                }
#pragma unroll
                for (int i = 0; i < FM; ++i)
#pragma unroll
                    for (int j = 0; j < FN; ++j)
                        acc[i][j] = __builtin_amdgcn_mfma_f32_16x16x32_bf16(af[i], bfr[j], acc[i][j], 0, 0, 0);
            }
        }
    }

    // C/D layout (m89/m91): col = lane&15, row = (lane>>4)*4 + reg
    const int col = lane & 15, qd = lane >> 4;

    if constexpr (EPI == 0 || EPI == 2) {
#pragma unroll
        for (int i = 0; i < FM; ++i)
#pragma unroll
            for (int r = 0; r < 4; ++r) {
                const long gm = m0 + wm + i * 16 + qd * 4 + r;
                float rowscale = 1.0f;
                if (EPI == 2) rowscale = 1.0f / g.srow[(long)z * 2048 + gm];
#pragma unroll
                for (int j = 0; j < FN; ++j) {
                    const long gn = n0 + wn + j * 16 + col;
                    const float x = acc[i][j][r];
                    float* o = (float*)g.out0 + (long)z * g.zso;
                    if (EPI == 0) o[gm * g.ldo + gn] = g.bias ? (x + g.bias[gn]) : x;
                    else          o[gm * g.ldo + gn] = fmaf(x, rowscale, g.bias[gn]);
                }
            }
    } else {
        if constexpr (EPI == 4) {
#pragma unroll
            for (int i = 0; i < FM; ++i)
#pragma unroll
                for (int j = 0; j < FN; ++j)
#pragma unroll
                    for (int r = 0; r < 4; ++r)
                        acc[i][j][r] = exp2f(acc[i][j][r] * g.escale);
#pragma unroll
            for (int i = 0; i < FM; ++i)
#pragma unroll
                for (int r = 0; r < 4; ++r) {
                    float s = 0.f;
#pragma unroll
                    for (int j = 0; j < FN; ++j) s += acc[i][j][r];
#pragma unroll
                    for (int off = 1; off < 16; off <<= 1) s += __shfl_xor(s, off, 64);
                    if ((lane & 15) == 0)
                        atomicAdd(g.Sout + (long)z * 2048 + m0 + wm + i * 16 + qd * 4 + r, s);
                }
        }
        __syncthreads();                 // staging LDS dead for all waves
        bf16* wa = (bf16*)smem + wave * WM * RSTR;
        constexpr int NP = (EPI == 1) ? 2 : 1;
        constexpr int CPR = WN / 8;      // 8-elem chunks per row
        constexpr int RPI = 64 / CPR;    // rows per store iteration
        static_assert(WM % RPI == 0, "repack rows");
#pragma unroll
        for (int pass = 0; pass < NP; ++pass) {
#pragma unroll
            for (int i = 0; i < FM; ++i)
#pragma unroll
                for (int j = 0; j < FN; ++j)
#pragma unroll
                    for (int r = 0; r < 4; ++r) {
                        const float x = acc[i][j][r];
                        bf16 v;
                        if (EPI == 1) {
                            const bf16 h = (bf16)x;
                            v = pass ? (bf16)(x - (float)h) : h;
                        } else {
                            v = (bf16)x;
                        }
                        wa[(i * 16 + qd * 4 + r) * RSTR + j * 16 + col] = v;
                    }
            bf16* outp = ((pass == 0) ? (bf16*)g.out0 : (bf16*)g.out1) + (long)z * g.zso;
#pragma unroll
            for (int t = 0; t < WM / RPI; ++t) {
                const int rr = t * RPI + (lane / CPR);
                const int cc = (lane % CPR) * 8;
                bf16x8 vv = *(const bf16x8*)&wa[rr * RSTR + cc];
                *(bf16x8*)(outp + (long)(m0 + wm + rr) * g.ldo + n0 + wn + cc) = vv;
            }
            if (NP == 2) asm volatile("s_waitcnt lgkmcnt(0)" ::: "memory");
        }
    }
}

// fp32 -> bf16 hi (always) + lo (if bit z of lomask); per-z length n[z];
// z==0 also zeros S (8192 f32)
struct SplitArgs {
    const float* x[4];
    bf16* h[4];
    bf16* l[4];
    float* S;
    long n[4];
    int lomask;
};
__global__ __launch_bounds__(256) void split_f32(SplitArgs s)
{
    const int z = blockIdx.z;
    if (s.S && z == 0 && blockIdx.x < 16) {
        const long si = (long)blockIdx.x * 256 + threadIdx.x;   // 16*256 float2 = 8192 f32
        ((float2*)s.S)[si] = make_float2(0.f, 0.f);
    }
    const long i = ((long)blockIdx.x * 256 + threadIdx.x) * 8;
    if (i >= s.n[z]) return;
    const float* x = s.x[z];
    float4 a = *(const float4*)(x + i);
    float4 b = *(const float4*)(x + i + 4);
    float vv[8] = {a.x, a.y, a.z, a.w, b.x, b.y, b.z, b.w};
    union { bf16 v[8]; bf16x8 v8; } uh, ul;
#pragma unroll
    for (int j = 0; j < 8; ++j) {
        bf16 hh = (bf16)vv[j];
        uh.v[j] = hh;
        ul.v[j] = (bf16)(vv[j] - (float)hh);
    }
    *(bf16x8*)(s.h[z] + i) = uh.v8;
    if (s.lomask & (1 << z)) *(bf16x8*)(s.l[z] + i) = ul.v8;
}

// W [512,512] fp32 -> transposed bf16 split: Th/Tl[d,e] = split(W[e,d]); z-batched
struct TransArgs {
    const float* x[3];
    bf16* th[3];
    bf16* tl[3];
};
__global__ __launch_bounds__(256) void transpose_split_w(TransArgs t3)
{
    __shared__ float t[64][65];
    const int z = blockIdx.z;
    const float* W = t3.x[z];
    bf16* Th = t3.th[z];
    bf16* Tl = t3.tl[z];
    const int e0 = blockIdx.y * 64, d0 = blockIdx.x * 64;
#pragma unroll 4
    for (int i = 0; i < 16; ++i) {
        int idx = i * 256 + threadIdx.x;
        int r = idx >> 6, c = idx & 63;
        t[r][c] = W[(long)(e0 + r) * 512 + d0 + c];
    }
    __syncthreads();
#pragma unroll
    for (int i = 0; i < 2; ++i) {
        int idx = i * 256 + threadIdx.x;          // 0..511
        int r = idx >> 3, c = (idx & 7) * 8;      // r = d offset, c = e offset
        union { bf16 v[8]; bf16x8 v8; } uh, ul;
#pragma unroll
        for (int j = 0; j < 8; ++j) {
            float x = t[c + j][r];
            bf16 hh = (bf16)x;
            uh.v[j] = hh;
            ul.v[j] = (bf16)(x - (float)hh);
        }
        *(bf16x8*)(Th + (long)(d0 + r) * 512 + e0 + c) = uh.v8;
        *(bf16x8*)(Tl + (long)(d0 + r) * 512 + e0 + c) = ul.v8;
    }
}

// ---------------- fp32 fallback (round-1, known-correct) ----------------
#define TILE 64
#define BKF 16
#define PADF 4

__global__ __launch_bounds__(256) void gemm_nt(
    const float* __restrict__ A, const float* __restrict__ B,
    float* __restrict__ C, const float* __restrict__ bias,
    int M, int N, int K, float alpha)
{
    __shared__ float As[BKF][TILE + PADF];
    __shared__ float Bs[BKF][TILE + PADF];
    const int tid = threadIdx.x;
    const int m0 = blockIdx.y * TILE;
    const int n0 = blockIdx.x * TILE;
    const int lr = tid >> 2;
    const int lk = (tid & 3) << 2;
    const int tm = (tid >> 4) << 2;
    const int tn = (tid & 15) << 2;

    float acc[4][4] = {};
    const float* ap = A + (long)(m0 + lr) * K + lk;
    const float* bp = B + (long)(n0 + lr) * K + lk;

    for (int k0 = 0; k0 < K; k0 += BKF) {
        float4 av = *(const float4*)(ap + k0);
        float4 bv = *(const float4*)(bp + k0);
        As[lk + 0][lr] = av.x; As[lk + 1][lr] = av.y;
        As[lk + 2][lr] = av.z; As[lk + 3][lr] = av.w;
        Bs[lk + 0][lr] = bv.x; Bs[lk + 1][lr] = bv.y;
        Bs[lk + 2][lr] = bv.z; Bs[lk + 3][lr] = bv.w;
        __syncthreads();
#pragma unroll
        for (int kk = 0; kk < BKF; ++kk) {
            float4 a4 = *(const float4*)&As[kk][tm];
            float4 b4 = *(const float4*)&Bs[kk][tn];
            float aa[4] = {a4.x, a4.y, a4.z, a4.w};
            float bb[4] = {b4.x, b4.y, b4.z, b4.w};
#pragma unroll
            for (int i = 0; i < 4; ++i)
#pragma unroll
                for (int j = 0; j < 4; ++j)
                    acc[i][j] = fmaf(aa[i], bb[j], acc[i][j]);
        }
        __syncthreads();
    }

    float4 b4 = make_float4(0.f, 0.f, 0.f, 0.f);
    if (bias) b4 = *(const float4*)(bias + n0 + tn);
#pragma unroll
    for (int i = 0; i < 4; ++i) {
        float4 o;
        o.x = fmaf(acc[i][0], alpha, b4.x);
        o.y = fmaf(acc[i][1], alpha, b4.y);
        o.z = fmaf(acc[i][2], alpha, b4.z);
        o.w = fmaf(acc[i][3], alpha, b4.w);
        *(float4*)(C + (long)(m0 + tm + i) * N + n0 + tn) = o;
    }
}

__global__ __launch_bounds__(256) void gemm_nn(
    const float* __restrict__ A, const float* __restrict__ B,
    float* __restrict__ C, int M, int N, int K)
{
    __shared__ float As[BKF][TILE + PADF];
    __shared__ float Bs[BKF][TILE + PADF];
    const int tid = threadIdx.x;
    const int m0 = blockIdx.y * TILE;
    const int n0 = blockIdx.x * TILE;
    const int lr = tid >> 2;
    const int lk = (tid & 3) << 2;
    const int bkk = tid >> 4;
    const int bn = (tid & 15) << 2;
    const int tm = (tid >> 4) << 2;
    const int tn = (tid & 15) << 2;

    float acc[4][4] = {};
    const float* ap = A + (long)(m0 + lr) * K + lk;
    const float* bp = B + (long)bkk * N + n0 + bn;

    for (int k0 = 0; k0 < K; k0 += BKF) {
        float4 av = *(const float4*)(ap + k0);
        As[lk + 0][lr] = av.x; As[lk + 1][lr] = av.y;
        As[lk + 2][lr] = av.z; As[lk + 3][lr] = av.w;
        float4 bv = *(const float4*)(bp + (long)k0 * N);
        *(float4*)&Bs[bkk][bn] = bv;
        __syncthreads();
#pragma unroll
        for (int kk = 0; kk < BKF; ++kk) {
            float4 a4 = *(const float4*)&As[kk][tm];
            float4 b4 = *(const float4*)&Bs[kk][tn];
            float aa[4] = {a4.x, a4.y, a4.z, a4.w};
            float bb[4] = {b4.x, b4.y, b4.z, b4.w};
#pragma unroll
            for (int i = 0; i < 4; ++i)
#pragma unroll
                for (int j = 0; j < 4; ++j)
                    acc[i][j] = fmaf(aa[i], bb[j], acc[i][j]);
        }
        __syncthreads();
    }

#pragma unroll
    for (int i = 0; i < 4; ++i) {
        float4 o = make_float4(acc[i][0], acc[i][1], acc[i][2], acc[i][3]);
        *(float4*)(C + (long)(m0 + tm + i) * N + n0 + tn) = o;
    }
}

__global__ __launch_bounds__(256) void softmax2048(float* __restrict__ E)
{
    const float c = 0.04419417382415922f * 1.44269504088896341f;
    float* p = E + (long)blockIdx.x * 2048;
    const int tid = threadIdx.x;
    float4 r0 = *(const float4*)(p + tid * 8);
    float4 r1 = *(const float4*)(p + tid * 8 + 4);
    float x[8] = {r0.x, r0.y, r0.z, r0.w, r1.x, r1.y, r1.z, r1.w};

    float m = x[0];
#pragma unroll
    for (int i = 1; i < 8; ++i) m = fmaxf(m, x[i]);
#pragma unroll
    for (int off = 32; off > 0; off >>= 1) m = fmaxf(m, __shfl_down(m, off, 64));

    __shared__ float red[4];
    const int lane = tid & 63, wid = tid >> 6;
    if (lane == 0) red[wid] = m;
    __syncthreads();
    m = fmaxf(fmaxf(red[0], red[1]), fmaxf(red[2], red[3]));

    float s = 0.f;
#pragma unroll
    for (int i = 0; i < 8; ++i) {
        x[i] = exp2f((x[i] - m) * c);
        s += x[i];
    }
#pragma unroll
    for (int off = 32; off > 0; off >>= 1) s += __shfl_down(s, off, 64);
    __syncthreads();
    if (lane == 0) red[wid] = s;
    __syncthreads();
    s = red[0] + red[1] + red[2] + red[3];
    const float inv = 1.0f / s;

    r0 = make_float4(x[0] * inv, x[1] * inv, x[2] * inv, x[3] * inv);
    r1 = make_float4(x[4] * inv, x[5] * inv, x[6] * inv, x[7] * inv);
    *(float4*)(p + tid * 8) = r0;
    *(float4*)(p + tid * 8 + 4) = r1;
}

// ------------------------------------------------------------------------

extern "C" void kernel_launch(void* const* d_in, const int* in_sizes, int n_in,
                              void* d_out, int out_size, void* d_ws, size_t ws_size,
                              hipStream_t stream)
{
    const int Bb = 4, Nn = 2048, E = 512;
    const int M = Bb * Nn;                       // 8192
    const float* value = (const float*)d_in[0];
    const float* key_  = (const float*)d_in[1];
    const float* query = (const float*)d_in[2];
    const float* Wq = (const float*)d_in[3];
    const float* Wk = (const float*)d_in[4];
    const float* Wv = (const float*)d_in[5];
    const float* Wo = (const float*)d_in[6];
    const float* bo = (const float*)d_in[7];
    float* out = (float*)d_out;

    const long ME = (long)M * E;                 // 4,194,304
    const long NE = (long)Nn * E;                // 1,048,576
    const long NN = (long)Nn * Nn;               // 4,194,304
    const long EE = (long)E * E;                 // 262,144
    const size_t EE2 = 524288;                   // EE bf16 bytes

    // weight block: [Woh|WkTh][Wol|WkTl][WvTh|WqTh][WvTl|WqTl][Wovh|Hh][Wovl|Hl]
    const size_t oWB  = 0;                        // 12 * EE2 = 6,291,456
    const size_t oQh  = oWB + 12 * EE2;           // ME*2 = 8,388,608
    const size_t oKh  = oQh + 8388608;
    const size_t oVh  = oKh + 8388608;
    const size_t oVl  = oVh + 8388608;
    const size_t oT   = oVl + 8388608;            // t: ME*2
    const size_t oU   = oT  + 8388608;            // 4*NN*2 = 33,554,432
    const size_t oS   = oU  + 33554432;           // 32,768
    const size_t oWV  = oS  + 32768;              // 4*NE*2 = 8,388,608
    const size_t REQ  = oWV + 8388608;            // 90,210,304

    if (ws_size < REQ) {
        // ---- fp32 fallback path (round-1, known-correct) ----
        float* q  = (float*)d_ws;
        float* k  = q  + ME;
        float* v  = k  + ME;
        float* en = v  + ME;
        float* ao = en + NN;
        const dim3 blk(256, 1, 1);
        gemm_nt<<<dim3(E / TILE, M / TILE, 1), blk, 0, stream>>>(query, Wq, q, nullptr, M, E, E, 1.0f);
        gemm_nt<<<dim3(E / TILE, M / TILE, 1), blk, 0, stream>>>(key_,  Wk, k, nullptr, M, E, E, 1.0f);
        gemm_nt<<<dim3(E / TILE, M / TILE, 1), blk, 0, stream>>>(value, Wv, v, nullptr, M, E, E, 1.0f);
        for (int b = 0; b < Bb; ++b) {
            const float* qb = q + (long)b * NE;
            const float* kb = k + (long)b * NE;
            const float* vb = v + (long)b * NE;
            float* aob = ao + (long)b * NE;
            gemm_nt<<<dim3(Nn / TILE, Nn / TILE, 1), blk, 0, stream>>>(qb, kb, en, nullptr, Nn, Nn, E, 1.0f);
            softmax2048<<<dim3(Nn, 1, 1), blk, 0, stream>>>(en);
            gemm_nn<<<dim3(E / TILE, Nn / TILE, 1), blk, 0, stream>>>(en, vb, aob, Nn, E, Nn);
        }
        gemm_nt<<<dim3(E / TILE, M / TILE, 1), blk, 0, stream>>>(ao, Wo, out, bo, M, E, E, 1.0f);
        return;
    }

    char* wb = (char*)d_ws + oWB;
    bf16* Woh  = (bf16*)(wb + 0 * EE2);
    bf16* WkTh = (bf16*)(wb + 1 * EE2);
    bf16* Wol  = (bf16*)(wb + 2 * EE2);
    bf16* WkTl = (bf16*)(wb + 3 * EE2);
    bf16* WvTh = (bf16*)(wb + 4 * EE2);
    bf16* WqTh = (bf16*)(wb + 5 * EE2);
    bf16* WvTl = (bf16*)(wb + 6 * EE2);
    bf16* WqTl = (bf16*)(wb + 7 * EE2);
    bf16* Wovh = (bf16*)(wb + 8 * EE2);
    bf16* Hh   = (bf16*)(wb + 9 * EE2);
    bf16* Wovl = (bf16*)(wb + 10 * EE2);   // (Hl at 11*EE2, computed but unused)
    bf16* qh   = (bf16*)((char*)d_ws + oQh);     // query bf16
    bf16* kh   = (bf16*)((char*)d_ws + oKh);     // key bf16
    bf16* vh   = (bf16*)((char*)d_ws + oVh);     // value hi
    bf16* vl   = (bf16*)((char*)d_ws + oVl);     // value lo
    bf16* tq   = (bf16*)((char*)d_ws + oT);      // t = query@H^T
    bf16* U    = (bf16*)((char*)d_ws + oU);      // [4][2048][2048]
    float* S   = (float*)((char*)d_ws + oS);     // [8192]
    bf16* WVh  = (bf16*)((char*)d_ws + oWV);     // [4][512][2048]

    // 1) converts: query,key (hi), value (hi+lo), Wo (hi+lo); zero S
    {
        SplitArgs s{};
        s.x[0] = query; s.x[1] = key_; s.x[2] = value; s.x[3] = Wo;
        s.h[0] = qh; s.h[1] = kh; s.h[2] = vh; s.h[3] = Woh;
        s.l[2] = vl; s.l[3] = Wol;
        s.S = S;
        s.n[0] = ME; s.n[1] = ME; s.n[2] = ME; s.n[3] = EE;
        s.lomask = 0b1100;
        split_f32<<<dim3((unsigned)(ME / 2048), 1, 4), 256, 0, stream>>>(s);
    }
    // 2) transposed splits: Wv, Wq, Wk
    {
        TransArgs t3{};
        t3.x[0] = Wv; t3.x[1] = Wq; t3.x[2] = Wk;
        t3.th[0] = WvTh; t3.th[1] = WqTh; t3.th[2] = WkTh;
        t3.tl[0] = WvTl; t3.tl[1] = WqTl; t3.tl[2] = WkTl;
        transpose_split_w<<<dim3(8, 8, 3), 256, 0, stream>>>(t3);
    }
    // 3) z=0: Wov = Wo@Wv ; z=1: H = Wk^T@Wq  (3-seg NT, split epilogue)
    {
        GArgs g{};
        g.a[0] = Woh;  g.a[1] = Woh;  g.a[2] = Wol;
        g.b[0] = WvTh; g.b[1] = WvTl; g.b[2] = WvTh;
        g.zsa = EE; g.zsb = EE; g.zso = EE;
        g.lda = E; g.ldb = E; g.ldo = E;
        g.out0 = Wovh; g.out1 = Wovl;
        gemm_mfma<64, 64, 3, 512, 1, 0><<<dim3(8, 8, 2), 256, 0, stream>>>(g);
    }
    // 4) t = query @ H^T  (plain 1-seg bf16)
    {
        GArgs g{};
        g.a[0] = qh;
        g.b[0] = Hh;
        g.lda = E; g.ldb = E; g.ldo = E;
        g.out0 = tq;
        gemm_mfma<128, 128, 1, 512, 3, 2><<<dim3(4, 64, 1), 256, 0, stream>>>(g);
    }
    // 5) energy: U = bf16(exp2((t.key^T)*c)), rowsums S via atomics
    {
        GArgs g{};
        g.a[0] = tq;
        g.b[0] = kh;
        g.zsa = NE; g.zsb = NE; g.zso = NN;
        g.lda = E; g.ldb = E; g.ldo = Nn;
        g.out0 = U; g.Sout = S;
        g.escale = 0.06375973295152033f; // (1/sqrt(512)) * log2(e)
        gemm_mfma<128, 128, 1, 512, 4, 1><<<dim3(16, 16, 4), 256, 0, stream>>>(g);
    }
    // 6) WV[f,k] = sum_e Wov[f,e] * value[k,e]  (3-seg — accuracy backbone)
    //    64x128 tile -> 512 blocks (2/CU): occupancy over per-block amortization
    {
        GArgs g{};
        g.a[0] = Wovh; g.a[1] = Wovh; g.a[2] = Wovl;
        g.b[0] = vh;   g.b[1] = vl;   g.b[2] = vh;
        g.zsa = 0; g.zsb = NE; g.zso = NE;
        g.lda = E; g.ldb = E; g.ldo = Nn;
        g.out0 = WVh;
        gemm_mfma<64, 128, 3, 512, 3, 0><<<dim3(Nn / 128, E / 64, Bb), 256, 0, stream>>>(g);
    }
    // 7) out[q,f] = (sum_k U[q,k] * WV[f,k]) / S[q] + bo[f]
    //    128x64 tile -> 512 blocks (2/CU), SWZ=3
    {
        GArgs g{};
        g.a[0] = U; g.b[0] = WVh;
        g.zsa = NN; g.zsb = NE; g.zso = NE;
        g.lda = Nn; g.ldb = Nn; g.ldo = E;
        g.out0 = out; g.bias = bo; g.srow = S;
        gemm_mfma<128, 64, 1, 2048, 2, 3><<<dim3(8, 16, 4), 256, 0, stream>>>(g);
    }
}